// Round 15
// baseline (219.609 us; speedup 1.0000x reference)
//
#include <hip/hip_runtime.h>
#include <cstdint>

#define SEQ 2048
#define BATCH 2
#define TOK 4096
#define HID 2048
#define NH 16
#define NKV 8
#define HD 128
#define QKV_LD 4096

using f16x8 = __attribute__((ext_vector_type(8))) _Float16;
using f32x4 = __attribute__((ext_vector_type(4))) float;

#define MFMA(a, b, c) __builtin_amdgcn_mfma_f32_16x16x32_f16(a, b, c, 0, 0, 0)

__device__ inline void gload16(const void* g, void* l) {
    __builtin_amdgcn_global_load_lds(
        (const __attribute__((address_space(1))) unsigned*)g,
        (__attribute__((address_space(3))) unsigned*)l, 16, 0, 0);
}

// hardware 2^x — bypasses the ocml exp2f library path (args bounded [-21,12])
__device__ inline float exp2_fast(float x) {
#if __has_builtin(__builtin_amdgcn_exp2f)
    return __builtin_amdgcn_exp2f(x);
#else
    float r;
    asm("v_exp_f32 %0, %1\n\ts_nop 1" : "=v"(r) : "v"(x));
    return r;
#endif
}

// pack two f32 -> one u32 of two f16 (v_cvt_pkrtz_f16_f32)
__device__ inline unsigned cvt_pk2(float a, float b) {
    auto h = __builtin_amdgcn_cvt_pkrtz(a, b);   // __fp16 ext_vector(2)
    return __builtin_bit_cast(unsigned, h);
}

// ---------------------------------------------------------------------------
// conv_all: fp32 operands -> plain row-major fp16: [hidden | Wq | Wk | Wv | Wo]
// ---------------------------------------------------------------------------
__global__ __launch_bounds__(256) void conv_all(
    const float* __restrict__ hidden, const float* __restrict__ Wq,
    const float* __restrict__ Wk, const float* __restrict__ Wv,
    const float* __restrict__ Wo, _Float16* __restrict__ HhG,
    _Float16* __restrict__ WallH, _Float16* __restrict__ WoH)
{
    const int bid = blockIdx.x;
    const float* src;
    _Float16* dst;
    int row;
    if (bid < 4096)      { row = bid;        src = hidden; dst = HhG; }
    else if (bid < 6144) { row = bid - 4096; src = Wq;     dst = WallH; }
    else if (bid < 7168) { row = bid - 6144; src = Wk;     dst = WallH + (size_t)2048 * HID; }
    else if (bid < 8192) { row = bid - 7168; src = Wv;     dst = WallH + (size_t)3072 * HID; }
    else                 { row = bid - 8192; src = Wo;     dst = WoH; }

    const int gch = threadIdx.x;            // chunk 0..255
    const float* s = src + (size_t)row * HID + gch * 8;
    float4 a = *(const float4*)s;
    float4 b = *(const float4*)(s + 4);
    f16x8 v;
    v[0] = (_Float16)a.x; v[1] = (_Float16)a.y;
    v[2] = (_Float16)a.z; v[3] = (_Float16)a.w;
    v[4] = (_Float16)b.x; v[5] = (_Float16)b.y;
    v[6] = (_Float16)b.z; v[7] = (_Float16)b.w;
    *(f16x8*)((char*)dst + (size_t)row * 4096 + gch * 16) = v;
}

// ---------------------------------------------------------------------------
// gemm256<HALF_OUT>: C[m][n] = sum_k A[m][k]*B[n][k], fp16 MFMA, fp32 accum.
// BM=BN=256, BK=64, 512 thr = 8 waves (2M x 4N). 128 KB LDS double-buffer.
// COUNTED-vmcnt pipeline (no vmcnt(0) in main loop):
//   read ALL frags of tile t -> regs; lgkmcnt(0)+barrier (buf free);
//   STAGE(buf, t+2); MFMA cluster (pure reg); vmcnt(8)+barrier
//   (waits only t+1's loads — issued one full tile ago; t+2's stay in flight)
// ---------------------------------------------------------------------------
template<bool HALF_OUT>
__global__ __launch_bounds__(512, 2) void gemm256(
    const _Float16* __restrict__ Ag, const _Float16* __restrict__ Bg,
    void* __restrict__ Cv, int ldc, int K)
{
    __shared__ char lds[2][4][16384];   // [buf][A0,A1,B0,B1][128 rows][128 B]

    const int tid = threadIdx.x;
    const int wv = tid >> 6, ln = tid & 63;
    const int wm = wv >> 2, wn = wv & 3;
    const int lr = ln & 15, lq = ln >> 4;
    const int bn = blockIdx.x, bm = blockIdx.y;

    f32x4 acc[8][4] = {};

    const size_t arow0 = (size_t)bm * 256;
    const size_t brow0 = (size_t)bn * 256;

    const int g = tid & 7;
    uint32_t offA[2][2], offB[2][2];        // [half][issue]
#pragma unroll
    for (int i = 0; i < 2; ++i) {
        const int row = (i * 512 + tid) >> 3;            // 0..127
        const uint32_t sw = (uint32_t)((g ^ (row & 7)) << 4);
        offA[0][i] = (uint32_t)((arow0 + row) * 4096) + sw;
        offA[1][i] = (uint32_t)((arow0 + 128 + row) * 4096) + sw;
        offB[0][i] = (uint32_t)((brow0 + row) * 4096) + sw;
        offB[1][i] = (uint32_t)((brow0 + 128 + row) * 4096) + sw;
    }
    const int dst0 = wv * 64 * 16;          // wave-uniform LDS base (+i*8192)

    const int swz0 = ((lq ^ (lr & 7)) << 4);
    const int swz1 = (((4 + lq) ^ (lr & 7)) << 4);

#define STAGE_ALL(bufsel, t)                                                   \
    { _Pragma("unroll")                                                        \
      for (int i = 0; i < 2; ++i) {                                            \
        gload16((const char*)Ag + offA[0][i] + (size_t)(t) * 128,              \
                &lds[bufsel][0][i * 8192 + dst0]);                             \
        gload16((const char*)Ag + offA[1][i] + (size_t)(t) * 128,              \
                &lds[bufsel][1][i * 8192 + dst0]);                             \
        gload16((const char*)Bg + offB[0][i] + (size_t)(t) * 128,              \
                &lds[bufsel][2][i * 8192 + dst0]);                             \
        gload16((const char*)Bg + offB[1][i] + (size_t)(t) * 128,              \
                &lds[bufsel][3][i * 8192 + dst0]);                             \
      } }

    STAGE_ALL(0, 0);                        // 8 loads (tile 0)
    STAGE_ALL(1, 1);                        // 8 loads (tile 1)
    asm volatile("s_waitcnt vmcnt(8)" ::: "memory");   // tile 0 landed
    __builtin_amdgcn_s_barrier();

    const int NT = K / 64;
    for (int t = 0; t < NT; ++t) {
        const int buf = t & 1;
        const char* Ab = &lds[buf][wm][0];
        const char* Bb = &lds[buf][2 + (wn >> 1)][(wn & 1) * 64 * 128];

        // read ALL fragments of tile t into registers
        f16x8 bfr[4][2], afr[8][2];
#pragma unroll
        for (int nj = 0; nj < 4; ++nj) {
            bfr[nj][0] = *(const f16x8*)(Bb + (nj * 16 + lr) * 128 + swz0);
            bfr[nj][1] = *(const f16x8*)(Bb + (nj * 16 + lr) * 128 + swz1);
        }
#pragma unroll
        for (int mi = 0; mi < 8; ++mi) {
            afr[mi][0] = *(const f16x8*)(Ab + (mi * 16 + lr) * 128 + swz0);
            afr[mi][1] = *(const f16x8*)(Ab + (mi * 16 + lr) * 128 + swz1);
        }
        asm volatile("s_waitcnt lgkmcnt(0)" ::: "memory");   // reads complete
        __builtin_amdgcn_s_barrier();       // all waves done reading buf

        if (t + 2 < NT) STAGE_ALL(buf, t + 2);   // refill freed buf

        __builtin_amdgcn_s_setprio(1);
#pragma unroll
        for (int mi = 0; mi < 8; ++mi)
#pragma unroll
            for (int nj = 0; nj < 4; ++nj) {
                acc[mi][nj] = MFMA(afr[mi][0], bfr[nj][0], acc[mi][nj]);
                acc[mi][nj] = MFMA(afr[mi][1], bfr[nj][1], acc[mi][nj]);
            }
        __builtin_amdgcn_s_setprio(0);

        // wait tile t+1 only (t+2's 8 loads remain in flight)
        if (t + 2 < NT) {
            asm volatile("s_waitcnt vmcnt(8)" ::: "memory");
        } else {
            asm volatile("s_waitcnt vmcnt(0)" ::: "memory");
        }
        __builtin_amdgcn_s_barrier();
    }
#undef STAGE_ALL

#pragma unroll
    for (int mi = 0; mi < 8; ++mi)
#pragma unroll
        for (int r = 0; r < 4; ++r) {
            const size_t rowoff =
                (size_t)(arow0 + wm * 128 + mi * 16 + lq * 4 + r) * ldc
                + brow0 + wn * 64 + lr;
            if constexpr (HALF_OUT) {
                _Float16* rowp = (_Float16*)Cv + rowoff;
#pragma unroll
                for (int nj = 0; nj < 4; ++nj)
                    rowp[nj * 16] = (_Float16)acc[mi][nj][r];
            } else {
                float* rowp = (float*)Cv + rowoff;
#pragma unroll
                for (int nj = 0; nj < 4; ++nj)
                    rowp[nj * 16] = acc[mi][nj][r];
            }
        }
}

// ---------------------------------------------------------------------------
// gemm256x128: BM=256, BN=128, fp32 out (out-projection, full-chip grid).
// Same counted-vmcnt pipeline; 6 loads/tile/thread -> vmcnt(6).
// ---------------------------------------------------------------------------
__global__ __launch_bounds__(512, 1) void gemm256x128(
    const _Float16* __restrict__ Ag, const _Float16* __restrict__ Bg,
    float* __restrict__ C, int ldc, int K)
{
    __shared__ char lds[2][3][16384];   // [buf][A0,A1,B][128 rows][128 B]

    const int tid = threadIdx.x;
    const int wv = tid >> 6, ln = tid & 63;
    const int wm = wv >> 1, wn = wv & 1;     // 4M x 2N
    const int lr = ln & 15, lq = ln >> 4;
    const int bn = blockIdx.x, bm = blockIdx.y;

    f32x4 acc[4][4] = {};

    const size_t arow0 = (size_t)bm * 256;
    const size_t brow0 = (size_t)bn * 128;

    const int g = tid & 7;
    uint32_t offA[2][2], offB[2];
#pragma unroll
    for (int i = 0; i < 2; ++i) {
        const int row = (i * 512 + tid) >> 3;
        const uint32_t sw = (uint32_t)((g ^ (row & 7)) << 4);
        offA[0][i] = (uint32_t)((arow0 + row) * 4096) + sw;
        offA[1][i] = (uint32_t)((arow0 + 128 + row) * 4096) + sw;
        offB[i]    = (uint32_t)((brow0 + row) * 4096) + sw;
    }
    const int dst0 = wv * 64 * 16;

    const int swz0 = ((lq ^ (lr & 7)) << 4);
    const int swz1 = (((4 + lq) ^ (lr & 7)) << 4);

#define STAGE_ALL2(bufsel, t)                                                  \
    { _Pragma("unroll")                                                        \
      for (int i = 0; i < 2; ++i) {                                            \
        gload16((const char*)Ag + offA[0][i] + (size_t)(t) * 128,              \
                &lds[bufsel][0][i * 8192 + dst0]);                             \
        gload16((const char*)Ag + offA[1][i] + (size_t)(t) * 128,              \
                &lds[bufsel][1][i * 8192 + dst0]);                             \
        gload16((const char*)Bg + offB[i] + (size_t)(t) * 128,                 \
                &lds[bufsel][2][i * 8192 + dst0]);                             \
      } }

    STAGE_ALL2(0, 0);                       // 6 loads
    STAGE_ALL2(1, 1);                       // 6 loads
    asm volatile("s_waitcnt vmcnt(6)" ::: "memory");
    __builtin_amdgcn_s_barrier();

    const int NT = K / 64;
    for (int t = 0; t < NT; ++t) {
        const int buf = t & 1;
        const char* Ab = &lds[buf][wm >> 1][(wm & 1) * 64 * 128];
        const char* Bb = &lds[buf][2][wn * 64 * 128];

        f16x8 bfr[4][2], afr[4][2];
#pragma unroll
        for (int nj = 0; nj < 4; ++nj) {
            bfr[nj][0] = *(const f16x8*)(Bb + (nj * 16 + lr) * 128 + swz0);
            bfr[nj][1] = *(const f16x8*)(Bb + (nj * 16 + lr) * 128 + swz1);
        }
#pragma unroll
        for (int mi = 0; mi < 4; ++mi) {
            afr[mi][0] = *(const f16x8*)(Ab + (mi * 16 + lr) * 128 + swz0);
            afr[mi][1] = *(const f16x8*)(Ab + (mi * 16 + lr) * 128 + swz1);
        }
        asm volatile("s_waitcnt lgkmcnt(0)" ::: "memory");
        __builtin_amdgcn_s_barrier();

        if (t + 2 < NT) STAGE_ALL2(buf, t + 2);

        __builtin_amdgcn_s_setprio(1);
#pragma unroll
        for (int mi = 0; mi < 4; ++mi)
#pragma unroll
            for (int nj = 0; nj < 4; ++nj) {
                acc[mi][nj] = MFMA(afr[mi][0], bfr[nj][0], acc[mi][nj]);
                acc[mi][nj] = MFMA(afr[mi][1], bfr[nj][1], acc[mi][nj]);
            }
        __builtin_amdgcn_s_setprio(0);

        if (t + 2 < NT) {
            asm volatile("s_waitcnt vmcnt(6)" ::: "memory");
        } else {
            asm volatile("s_waitcnt vmcnt(0)" ::: "memory");
        }
        __builtin_amdgcn_s_barrier();
    }
#undef STAGE_ALL2

#pragma unroll
    for (int mi = 0; mi < 4; ++mi)
#pragma unroll
        for (int r = 0; r < 4; ++r) {
            float* rowp = C + (size_t)(arow0 + wm * 64 + mi * 16 + lq * 4 + r) * ldc
                          + brow0 + wn * 64 + lr;
#pragma unroll
            for (int nj = 0; nj < 4; ++nj)
                rowp[nj * 16] = acc[mi][nj][r];
        }
}

// ---------------------------------------------------------------------------
// norm_rope: reads fp16 P. q heads -> RMS+RoPE, pre-scaled by scale*log2e,
// fp16 to QhG (plain); k heads -> RMS+RoPE, fp16 pre-swizzled to KhG.
// ---------------------------------------------------------------------------
__global__ __launch_bounds__(256) void norm_rope(
    const _Float16* __restrict__ P, const float* __restrict__ cosb,
    const float* __restrict__ sinb, const float* __restrict__ qw,
    const float* __restrict__ kw, _Float16* __restrict__ QhG,
    _Float16* __restrict__ KhG)
{
    const int t    = blockIdx.y;
    const int wave = threadIdx.x >> 6;
    const int lane = threadIdx.x & 63;
    const int hid  = blockIdx.x * 4 + wave; // 0..23
    const float QS = 0.08838834764831845f * 1.4426950408889634f;

    const _Float16* ptr;
    const float* w;
    if (hid < NH) { ptr = P + (size_t)t * QKV_LD + hid * HD;              w = qw; }
    else          { ptr = P + (size_t)t * QKV_LD + HID + (hid - NH) * HD; w = kw; }

    float x1 = (float)ptr[lane];
    float x2 = (float)ptr[lane + 64];
    float ss = x1 * x1 + x2 * x2;
#pragma unroll
    for (int off = 1; off < 64; off <<= 1) ss += __shfl_xor(ss, off);
    const float r = rsqrtf(ss * (1.f / 128.f) + 1e-6f);
    const float n1 = x1 * r * w[lane];
    const float n2 = x2 * r * w[lane + 64];

    const float* cp = cosb + (size_t)t * HD;
    const float* sp = sinb + (size_t)t * HD;
    const float o1 = n1 * cp[lane]      - n2 * sp[lane];
    const float o2 = n2 * cp[lane + 64] + n1 * sp[lane + 64];

    if (hid < NH) {
        _Float16* qrow = QhG + (size_t)t * HID + hid * HD;
        qrow[lane]      = (_Float16)(o1 * QS);
        qrow[lane + 64] = (_Float16)(o2 * QS);
    } else {
        const int b = t / SEQ, s = t % SEQ, kv = hid - NH;
        char* ph = (char*)KhG + ((size_t)(b * NKV + kv) * SEQ + s) * 256;
        const int s7 = s & 7;
        const int d1 = lane, d2 = lane + 64;
        *(_Float16*)(ph + (((d1 >> 3) ^ s7) << 4) + ((d1 & 7) << 1)) = (_Float16)o1;
        *(_Float16*)(ph + (((d2 >> 3) ^ s7) << 4) + ((d2 & 7) << 1)) = (_Float16)o2;
    }
}

// ---------------------------------------------------------------------------
// conv_v: fp16 V rows of P -> transposed fp16 VtG [b][kv][d=128][s=2048],
// pre-swizzled (8 chunks per 64-key group, chunk ^= d&7).
// ---------------------------------------------------------------------------
__global__ __launch_bounds__(256) void conv_v(
    const _Float16* __restrict__ P, _Float16* __restrict__ VtG)
{
    __shared__ _Float16 Ts[64][136];    // 272B rows (16B-aligned)
    const int kb = blockIdx.x;      // 64-token block over TOK
    const int kv = blockIdx.y;
    const int tid = threadIdx.x;

#pragma unroll
    for (int r = 0; r < 4; ++r) {
        const int idx = tid + r * 256;      // 0..1023
        const int row = idx >> 4, c8 = idx & 15;
        *(f16x8*)&Ts[row][c8 * 8] =
            *(const f16x8*)(P + (size_t)(kb * 64 + row) * QKV_LD
                            + HID + NKV * HD + kv * HD + c8 * 8);
    }
    __syncthreads();

    const int b  = (kb * 64) / SEQ;
    const int s0 = (kb * 64) % SEQ;
#pragma unroll
    for (int w = 0; w < 4; ++w) {
        const int idx = tid + w * 256;      // 0..1023
        const int d = idx >> 3, c = idx & 7;
        f16x8 pk;
#pragma unroll
        for (int kk = 0; kk < 8; ++kk) pk[kk] = Ts[c * 8 + kk][d];
        char* dst = (char*)VtG + ((size_t)(b * NKV + kv) * 128 + d) * 4096
                    + ((s0 >> 3) + (c ^ (d & 7))) * 16;
        *(f16x8*)dst = pk;
    }
}

// ---------------------------------------------------------------------------
// flash_f16: R14 (best measured, 84 µs): K dbuf LDS, V single LDS,
// midbar=vmcnt(4), end-of-iteration staging, XCD-chunked swizzle,
// SWAPPED QK^T (lane-local P-row), cvt_pkrtz P-pack, static-bias softmax.
// ---------------------------------------------------------------------------
__global__ __launch_bounds__(256, 2) void flash_f16(
    const _Float16* __restrict__ QhG, const _Float16* __restrict__ KhG,
    const _Float16* __restrict__ VtG, _Float16* __restrict__ OH)
{
    __shared__ char KhL[2][16384];          // [key 64][chunk^swz 16]*16B
    __shared__ char VtL[16384];             // [d 128][chunk^swz 8]*16B
    __shared__ char PlB[4][5120];           // [wave][q 32 rows x 160 B]

    // XCD-chunked swizzle: id%8 = XCD -> give each XCD 64 consecutive tiles
    const int id  = blockIdx.x + 16 * (blockIdx.y + 16 * blockIdx.z);
    const int swz = (id & 7) * 64 + (id >> 3);
    const int qt = swz & 15, h = (swz >> 4) & 15, b = swz >> 8;

    const int hkv = h >> 1;
    const int tid = threadIdx.x, wv = tid >> 6, ln = tid & 63;
    const int lr = ln & 15, lq = ln >> 4;
    const int qbase = qt * 128 + wv * 32;
    const float BIAS = 3.0f * 1.4426950408889634f;   // 3*log2e

    // Q fragments (pre-scaled by scale*log2e in norm_rope)
    f16x8 qh[2][4];
#pragma unroll
    for (int mi = 0; mi < 2; ++mi)
#pragma unroll
        for (int kc = 0; kc < 4; ++kc)
            qh[mi][kc] = *(const f16x8*)(QhG
                + (size_t)(b * SEQ + qbase + mi * 16 + lr) * HID
                + h * HD + kc * 32 + lq * 8);

    f32x4 o_[2][8] = {};
    float rs[2] = {0.f, 0.f};               // per-lane: q-row mi*16 + lr

    const size_t krow = (size_t)(b * NKV + hkv) * SEQ;   // 256B rows
    const size_t vrow = (size_t)(b * NKV + hkv) * 128;   // 4096B rows

    const char* kg[4];
    const char* vg[4];
    int dofs[4];
#pragma unroll
    for (int r = 0; r < 4; ++r) {
        const int idx = tid + r * 256;
        kg[r] = (const char*)KhG + (krow + (idx >> 4)) * 256 + (idx & 15) * 16;
        vg[r] = (const char*)VtG + (vrow + (idx >> 3)) * 4096 + (idx & 7) * 16;
        dofs[r] = (r * 256 + wv * 64) * 16;
    }

#define STAGE_K(buf, kt)                                                      \
    { _Pragma("unroll")                                                       \
      for (int r = 0; r < 4; ++r)                                             \
          gload16(kg[r] + (size_t)(kt) * 16384, &KhL[buf][dofs[r]]); }
#define STAGE_V(kt)                                                           \
    { _Pragma("unroll")                                                       \
      for (int r = 0; r < 4; ++r)                                             \
          gload16(vg[r] + (kt) * 128, &VtL[dofs[r]]); }

    STAGE_K(0, 0);
    STAGE_V(0);
    STAGE_K(1, 1);
    __syncthreads();            // drains vmcnt(0): K(0), V(0), K(1) ready

    const int NT = SEQ / 64;
    for (int kt = 0; kt < NT; ++kt) {
        const int buf = kt & 1;

        // QK^T (SWAPPED): lane holds P-row q = mi*16 + lr,
        // keys nt*16 + lq*4 + r. acc pre-biased by -3*log2e.
        f32x4 s[2][4];
        __builtin_amdgcn_s_setprio(1);
#pragma unroll
        for (int nt = 0; nt < 4; ++nt) {
            const int key = nt * 16 + lr;
            f16x8 kh[4];
#pragma unroll
            for (int kc = 0; kc < 4; ++kc)
                kh[kc] = *(f16x8*)(&KhL[buf][key * 256 +
                                   ((((kc * 4 + lq) ^ (lr & 7))) << 4)]);
#pragma unroll
            for (int mi = 0; mi < 2; ++mi) {
                f32x4 sa = {-BIAS, -BIAS, -BIAS, -BIAS};
#pragma unroll
                for (int kc = 0; kc < 4; ++kc)
                    sa = MFMA(kh[kc], qh[mi][kc], sa);   // A=K, B=Q
                s[mi][nt] = sa;
            }
        }
        __builtin_amdgcn_s_setprio(0);

        // p = 2^s; lane-local row sums; pack pairs -> ds_write_b64
#pragma unroll
        for (int mi = 0; mi < 2; ++mi) {
            float acc = 0.f;
            char* rowp = &PlB[wv][(mi * 16 + lr) * 160 + lq * 8];
#pragma unroll
            for (int nt = 0; nt < 4; ++nt) {
                const float p0 = exp2_fast(s[mi][nt][0]);
                const float p1 = exp2_fast(s[mi][nt][1]);
                const float p2 = exp2_fast(s[mi][nt][2]);
                const float p3 = exp2_fast(s[mi][nt][3]);
                acc += (p0 + p1) + (p2 + p3);
                *(uint2*)(rowp + nt * 32) =
                    make_uint2(cvt_pk2(p0, p1), cvt_pk2(p2, p3));
            }
            rs[mi] += acc;
        }
        f16x8 pa[2][2];
#pragma unroll
        for (int mi = 0; mi < 2; ++mi) {
            pa[mi][0] = *(f16x8*)&PlB[wv][(mi * 16 + lr) * 160 + lq * 16];
            pa[mi][1] = *(f16x8*)&PlB[wv][(mi * 16 + lr) * 160 + 64 + lq * 16];
        }

        // midbar: wait V(kt) only (4 oldest of 8 outstanding); K(kt+1) flies
        if (kt + 1 < NT) {
            asm volatile("s_waitcnt vmcnt(4)" ::: "memory");
        } else {
            asm volatile("s_waitcnt vmcnt(0)" ::: "memory");
        }
        __builtin_amdgcn_s_barrier();

        // PV accumulate: O[32 q][128 d] += P(32x64) x V(64x128)
        __builtin_amdgcn_s_setprio(1);
#pragma unroll
        for (int nt2 = 0; nt2 < 8; ++nt2) {
            const int d0 = nt2 * 16 + lr;
            f16x8 v0 = *(f16x8*)(&VtL[d0 * 128 + ((lq ^ (d0 & 7)) << 4)]);
            f16x8 v1 = *(f16x8*)(&VtL[d0 * 128 + (((4 + lq) ^ (d0 & 7)) << 4)]);
#pragma unroll
            for (int mi = 0; mi < 2; ++mi) {
                o_[mi][nt2] = MFMA(pa[mi][0], v0, o_[mi][nt2]);
                o_[mi][nt2] = MFMA(pa[mi][1], v1, o_[mi][nt2]);
            }
        }
        __builtin_amdgcn_s_setprio(0);

        __syncthreads();        // endbar: drains K(kt+1); V-reads done

        if (kt + 1 < NT) STAGE_V(kt + 1);       // drains at next midbar
        if (kt + 2 < NT) STAGE_K(buf, kt + 2);  // drains at next endbar
    }

    // lane's rs[mi] covers its lq-slice of q-row mi*16+lr: reduce over lq
    float inv[2];
#pragma unroll
    for (int mi = 0; mi < 2; ++mi) {
        float v = rs[mi];
        v += __shfl_xor(v, 16);
        v += __shfl_xor(v, 32);
        inv[mi] = 1.0f / v;
    }
    // redistribute to output-row owners: row q = mi*16 + lq*4 + r is held
    // (as inv[mi]) by lanes with lr == lq*4 + r (any lq group)
    float invq[2][4];
#pragma unroll
    for (int mi = 0; mi < 2; ++mi)
#pragma unroll
        for (int r = 0; r < 4; ++r)
            invq[mi][r] = __shfl(inv[mi], (ln & 48) | (lq * 4 + r));

    // plain row-major fp16 output [token][2048]
#pragma unroll
    for (int mi = 0; mi < 2; ++mi)
#pragma unroll
        for (int r = 0; r < 4; ++r) {
            const int R = b * SEQ + qbase + mi * 16 + lq * 4 + r;
            _Float16* rowp = OH + (size_t)R * HID + h * HD + lr;
#pragma unroll
            for (int nt2 = 0; nt2 < 8; ++nt2)
                rowp[nt2 * 16] = (_Float16)(o_[mi][nt2][r] * invq[mi][r]);
        }
#undef STAGE_K
#undef STAGE_V
}

// ---------------------------------------------------------------------------
extern "C" void kernel_launch(void* const* d_in, const int* in_sizes, int n_in,
                              void* d_out, int out_size, void* d_ws, size_t ws_size,
                              hipStream_t stream)
{
    (void)in_sizes; (void)n_in; (void)out_size; (void)ws_size;
    const float* hidden = (const float*)d_in[0];
    const float* cosb   = (const float*)d_in[1];
    const float* sinb   = (const float*)d_in[2];
    const float* Wq     = (const float*)d_in[3];
    const float* Wk     = (const float*)d_in[4];
    const float* Wv     = (const float*)d_in[5];
    const float* Wo     = (const float*)d_in[6];
    const float* qw     = (const float*)d_in[7];
    const float* kw     = (const float*)d_in[8];
    float* out = (float*)d_out;

    char* ws = (char*)d_ws;
    const size_t MB = 1ull << 20;
    _Float16*  P16   = (_Float16*)(ws);               // 32 MB [4096][4096] fp16
    _Float16*  attnH = (_Float16*)(ws + 32  * MB);    // 16 MB [4096][2048] plain
    _Float16*  HhG   = (_Float16*)(ws + 48  * MB);    // 16 MB [4096][2048] plain
    _Float16*  WallH = (_Float16*)(ws + 64  * MB);    // 16 MB (Wq|Wk|Wv)
    _Float16*  WoH   = (_Float16*)(ws + 80  * MB);    //  8 MB [2048][2048] plain
    _Float16*  KhG   = (_Float16*)(ws + 88  * MB);    //  8 MB (flash-swizzled)
    _Float16*  VtG   = (_Float16*)(ws + 96  * MB);    //  8 MB (flash-swizzled)
    _Float16*  QhG   = (_Float16*)(ws + 104 * MB);    // 16 MB [4096][2048] plain

    const dim3 blk(256);
    conv_all<<<10240, blk, 0, stream>>>(hidden, Wq, Wk, Wv, Wo, HhG, WallH, WoH);

    // fused QKV projection -> fp16 P
    gemm256<true><<<dim3(16, 16), dim3(512), 0, stream>>>(HhG, WallH, P16, QKV_LD, HID);

    norm_rope<<<dim3(6, TOK), blk, 0, stream>>>(P16, cosb, sinb, qw, kw, QhG, KhG);
    conv_v<<<dim3(TOK / 64, NKV), blk, 0, stream>>>(P16, VtG);

    flash_f16<<<dim3(SEQ / 128, NH, BATCH), blk, 0, stream>>>(QhG, KhG, VtG, attnH);

    // output projection: 256x128 tiles, full-chip grid
    gemm256x128<<<dim3(16, 16), dim3(512), 0, stream>>>(attnH, WoH, out, HID, HID);
}

// Round 16
// 209.318 us; speedup vs baseline: 1.0492x; 1.0492x over previous
//
#include <hip/hip_runtime.h>
#include <cstdint>

#define SEQ 2048
#define BATCH 2
#define TOK 4096
#define HID 2048
#define NH 16
#define NKV 8
#define HD 128
#define QKV_LD 4096

using f16x8 = __attribute__((ext_vector_type(8))) _Float16;
using f32x4 = __attribute__((ext_vector_type(4))) float;

#define MFMA(a, b, c) __builtin_amdgcn_mfma_f32_16x16x32_f16(a, b, c, 0, 0, 0)

__device__ inline void gload16(const void* g, void* l) {
    __builtin_amdgcn_global_load_lds(
        (const __attribute__((address_space(1))) unsigned*)g,
        (__attribute__((address_space(3))) unsigned*)l, 16, 0, 0);
}

// hardware 2^x — bypasses the ocml exp2f library path (args bounded [-21,12])
__device__ inline float exp2_fast(float x) {
#if __has_builtin(__builtin_amdgcn_exp2f)
    return __builtin_amdgcn_exp2f(x);
#else
    float r;
    asm("v_exp_f32 %0, %1\n\ts_nop 1" : "=v"(r) : "v"(x));
    return r;
#endif
}

// pack two f32 -> one u32 of two f16 (v_cvt_pkrtz_f16_f32)
__device__ inline unsigned cvt_pk2(float a, float b) {
    auto h = __builtin_amdgcn_cvt_pkrtz(a, b);   // __fp16 ext_vector(2)
    return __builtin_bit_cast(unsigned, h);
}

// ---------------------------------------------------------------------------
// conv_all: fp32 operands -> plain row-major fp16: [hidden | Wq | Wk | Wv | Wo]
// ---------------------------------------------------------------------------
__global__ __launch_bounds__(256) void conv_all(
    const float* __restrict__ hidden, const float* __restrict__ Wq,
    const float* __restrict__ Wk, const float* __restrict__ Wv,
    const float* __restrict__ Wo, _Float16* __restrict__ HhG,
    _Float16* __restrict__ WallH, _Float16* __restrict__ WoH)
{
    const int bid = blockIdx.x;
    const float* src;
    _Float16* dst;
    int row;
    if (bid < 4096)      { row = bid;        src = hidden; dst = HhG; }
    else if (bid < 6144) { row = bid - 4096; src = Wq;     dst = WallH; }
    else if (bid < 7168) { row = bid - 6144; src = Wk;     dst = WallH + (size_t)2048 * HID; }
    else if (bid < 8192) { row = bid - 7168; src = Wv;     dst = WallH + (size_t)3072 * HID; }
    else                 { row = bid - 8192; src = Wo;     dst = WoH; }

    const int gch = threadIdx.x;            // chunk 0..255
    const float* s = src + (size_t)row * HID + gch * 8;
    float4 a = *(const float4*)s;
    float4 b = *(const float4*)(s + 4);
    f16x8 v;
    v[0] = (_Float16)a.x; v[1] = (_Float16)a.y;
    v[2] = (_Float16)a.z; v[3] = (_Float16)a.w;
    v[4] = (_Float16)b.x; v[5] = (_Float16)b.y;
    v[6] = (_Float16)b.z; v[7] = (_Float16)b.w;
    *(f16x8*)((char*)dst + (size_t)row * 4096 + gch * 16) = v;
}

// ---------------------------------------------------------------------------
// gemm256<HALF_OUT>: C[m][n] = sum_k A[m][k]*B[n][k], fp16 MFMA, fp32 accum.
// BM=BN=256, BK=64, 512 thr = 8 waves (2M x 4N). 128 KB LDS double-buffer,
// one vmcnt(0)+barrier per K-tile, stage t+1 issued mid-tile. (R14 form.)
// ---------------------------------------------------------------------------
template<bool HALF_OUT>
__global__ __launch_bounds__(512, 2) void gemm256(
    const _Float16* __restrict__ Ag, const _Float16* __restrict__ Bg,
    void* __restrict__ Cv, int ldc, int K)
{
    __shared__ char lds[2][4][16384];   // [buf][A0,A1,B0,B1][128 rows][128 B]

    const int tid = threadIdx.x;
    const int wv = tid >> 6, ln = tid & 63;
    const int wm = wv >> 2, wn = wv & 3;
    const int lr = ln & 15, lq = ln >> 4;
    const int bn = blockIdx.x, bm = blockIdx.y;

    f32x4 acc[8][4] = {};

    const size_t arow0 = (size_t)bm * 256;
    const size_t brow0 = (size_t)bn * 256;

    const int g = tid & 7;
    uint32_t offA[2][2], offB[2][2];        // [half][issue]
#pragma unroll
    for (int i = 0; i < 2; ++i) {
        const int row = (i * 512 + tid) >> 3;            // 0..127
        const uint32_t sw = (uint32_t)((g ^ (row & 7)) << 4);
        offA[0][i] = (uint32_t)((arow0 + row) * 4096) + sw;
        offA[1][i] = (uint32_t)((arow0 + 128 + row) * 4096) + sw;
        offB[0][i] = (uint32_t)((brow0 + row) * 4096) + sw;
        offB[1][i] = (uint32_t)((brow0 + 128 + row) * 4096) + sw;
    }
    const int dst0 = wv * 64 * 16;          // wave-uniform LDS base (+i*8192)

    const int swz0 = ((lq ^ (lr & 7)) << 4);
    const int swz1 = (((4 + lq) ^ (lr & 7)) << 4);

#define STAGE_ALL(bufsel, t)                                                   \
    { _Pragma("unroll")                                                        \
      for (int i = 0; i < 2; ++i) {                                            \
        gload16((const char*)Ag + offA[0][i] + (size_t)(t) * 128,              \
                &lds[bufsel][0][i * 8192 + dst0]);                             \
        gload16((const char*)Ag + offA[1][i] + (size_t)(t) * 128,              \
                &lds[bufsel][1][i * 8192 + dst0]);                             \
        gload16((const char*)Bg + offB[0][i] + (size_t)(t) * 128,              \
                &lds[bufsel][2][i * 8192 + dst0]);                             \
        gload16((const char*)Bg + offB[1][i] + (size_t)(t) * 128,              \
                &lds[bufsel][3][i * 8192 + dst0]);                             \
      } }

    STAGE_ALL(0, 0);
    asm volatile("s_waitcnt vmcnt(0)" ::: "memory");
    __builtin_amdgcn_s_barrier();

    const int NT = K / 64;
    for (int t = 0; t < NT; ++t) {
        const int buf = t & 1;
        const char* Ab = &lds[buf][wm][0];
        const char* Bb = &lds[buf][2 + (wn >> 1)][(wn & 1) * 64 * 128];

        f16x8 bfr[4][2];
#pragma unroll
        for (int nj = 0; nj < 4; ++nj) {
            bfr[nj][0] = *(const f16x8*)(Bb + (nj * 16 + lr) * 128 + swz0);
            bfr[nj][1] = *(const f16x8*)(Bb + (nj * 16 + lr) * 128 + swz1);
        }

        if (t + 1 < NT) STAGE_ALL(buf ^ 1, t + 1);   // early issue, late drain

        __builtin_amdgcn_s_setprio(1);
#pragma unroll
        for (int mi = 0; mi < 8; ++mi) {
            f16x8 a0 = *(const f16x8*)(Ab + (mi * 16 + lr) * 128 + swz0);
            f16x8 a1 = *(const f16x8*)(Ab + (mi * 16 + lr) * 128 + swz1);
#pragma unroll
            for (int nj = 0; nj < 4; ++nj) {
                acc[mi][nj] = MFMA(a0, bfr[nj][0], acc[mi][nj]);
                acc[mi][nj] = MFMA(a1, bfr[nj][1], acc[mi][nj]);
            }
        }
        __builtin_amdgcn_s_setprio(0);

        asm volatile("s_waitcnt vmcnt(0)" ::: "memory");
        __builtin_amdgcn_s_barrier();
    }
#undef STAGE_ALL

#pragma unroll
    for (int mi = 0; mi < 8; ++mi)
#pragma unroll
        for (int r = 0; r < 4; ++r) {
            const size_t rowoff =
                (size_t)(arow0 + wm * 128 + mi * 16 + lq * 4 + r) * ldc
                + brow0 + wn * 64 + lr;
            if constexpr (HALF_OUT) {
                _Float16* rowp = (_Float16*)Cv + rowoff;
#pragma unroll
                for (int nj = 0; nj < 4; ++nj)
                    rowp[nj * 16] = (_Float16)acc[mi][nj][r];
            } else {
                float* rowp = (float*)Cv + rowoff;
#pragma unroll
                for (int nj = 0; nj < 4; ++nj)
                    rowp[nj * 16] = acc[mi][nj][r];
            }
        }
}

// ---------------------------------------------------------------------------
// gemm256x128: BM=256, BN=128, fp32 out (out-projection, full-chip grid).
// R14 form: one vmcnt(0)+barrier per K-tile.
// ---------------------------------------------------------------------------
__global__ __launch_bounds__(512, 1) void gemm256x128(
    const _Float16* __restrict__ Ag, const _Float16* __restrict__ Bg,
    float* __restrict__ C, int ldc, int K)
{
    __shared__ char lds[2][3][16384];   // [buf][A0,A1,B][128 rows][128 B]

    const int tid = threadIdx.x;
    const int wv = tid >> 6, ln = tid & 63;
    const int wm = wv >> 1, wn = wv & 1;     // 4M x 2N
    const int lr = ln & 15, lq = ln >> 4;
    const int bn = blockIdx.x, bm = blockIdx.y;

    f32x4 acc[4][4] = {};

    const size_t arow0 = (size_t)bm * 256;
    const size_t brow0 = (size_t)bn * 128;

    const int g = tid & 7;
    uint32_t offA[2][2], offB[2];
#pragma unroll
    for (int i = 0; i < 2; ++i) {
        const int row = (i * 512 + tid) >> 3;
        const uint32_t sw = (uint32_t)((g ^ (row & 7)) << 4);
        offA[0][i] = (uint32_t)((arow0 + row) * 4096) + sw;
        offA[1][i] = (uint32_t)((arow0 + 128 + row) * 4096) + sw;
        offB[i]    = (uint32_t)((brow0 + row) * 4096) + sw;
    }
    const int dst0 = wv * 64 * 16;

    const int swz0 = ((lq ^ (lr & 7)) << 4);
    const int swz1 = (((4 + lq) ^ (lr & 7)) << 4);

#define STAGE_ALL2(bufsel, t)                                                  \
    { _Pragma("unroll")                                                        \
      for (int i = 0; i < 2; ++i) {                                            \
        gload16((const char*)Ag + offA[0][i] + (size_t)(t) * 128,              \
                &lds[bufsel][0][i * 8192 + dst0]);                             \
        gload16((const char*)Ag + offA[1][i] + (size_t)(t) * 128,              \
                &lds[bufsel][1][i * 8192 + dst0]);                             \
        gload16((const char*)Bg + offB[i] + (size_t)(t) * 128,                 \
                &lds[bufsel][2][i * 8192 + dst0]);                             \
      } }

    STAGE_ALL2(0, 0);
    asm volatile("s_waitcnt vmcnt(0)" ::: "memory");
    __builtin_amdgcn_s_barrier();

    const int NT = K / 64;
    for (int t = 0; t < NT; ++t) {
        const int buf = t & 1;
        const char* Ab = &lds[buf][wm >> 1][(wm & 1) * 64 * 128];
        const char* Bb = &lds[buf][2][wn * 64 * 128];

        f16x8 bfr[4][2];
#pragma unroll
        for (int nj = 0; nj < 4; ++nj) {
            bfr[nj][0] = *(const f16x8*)(Bb + (nj * 16 + lr) * 128 + swz0);
            bfr[nj][1] = *(const f16x8*)(Bb + (nj * 16 + lr) * 128 + swz1);
        }

        if (t + 1 < NT) STAGE_ALL2(buf ^ 1, t + 1);

        __builtin_amdgcn_s_setprio(1);
#pragma unroll
        for (int mi = 0; mi < 4; ++mi) {
            f16x8 a0 = *(const f16x8*)(Ab + (mi * 16 + lr) * 128 + swz0);
            f16x8 a1 = *(const f16x8*)(Ab + (mi * 16 + lr) * 128 + swz1);
#pragma unroll
            for (int nj = 0; nj < 4; ++nj) {
                acc[mi][nj] = MFMA(a0, bfr[nj][0], acc[mi][nj]);
                acc[mi][nj] = MFMA(a1, bfr[nj][1], acc[mi][nj]);
            }
        }
        __builtin_amdgcn_s_setprio(0);

        asm volatile("s_waitcnt vmcnt(0)" ::: "memory");
        __builtin_amdgcn_s_barrier();
    }
#undef STAGE_ALL2

#pragma unroll
    for (int mi = 0; mi < 4; ++mi)
#pragma unroll
        for (int r = 0; r < 4; ++r) {
            float* rowp = C + (size_t)(arow0 + wm * 64 + mi * 16 + lq * 4 + r) * ldc
                          + brow0 + wn * 64 + lr;
#pragma unroll
            for (int nj = 0; nj < 4; ++nj)
                rowp[nj * 16] = acc[mi][nj][r];
        }
}

// ---------------------------------------------------------------------------
// post_qkv: fused norm_rope + conv_v (one dispatch).
// Blocks [0, 6*TOK): RMS+RoPE. q heads -> QhG (pre-scaled fp16);
//   k heads -> KhG pre-swizzled fp16.
// Blocks [6*TOK, 6*TOK + 512): V transpose -> VtG pre-swizzled fp16.
// ---------------------------------------------------------------------------
__global__ __launch_bounds__(256) void post_qkv(
    const _Float16* __restrict__ P, const float* __restrict__ cosb,
    const float* __restrict__ sinb, const float* __restrict__ qw,
    const float* __restrict__ kw, _Float16* __restrict__ QhG,
    _Float16* __restrict__ KhG, _Float16* __restrict__ VtG)
{
    __shared__ _Float16 Ts[64][136];
    const int bid = blockIdx.x;

    if (bid < 6 * TOK) {
        // ------------------- norm + rope -------------------
        const int t    = bid / 6;
        const int xb   = bid % 6;
        const int wave = threadIdx.x >> 6;
        const int lane = threadIdx.x & 63;
        const int hid  = xb * 4 + wave;     // 0..23
        const float QS = 0.08838834764831845f * 1.4426950408889634f;

        const _Float16* ptr;
        const float* w;
        if (hid < NH) { ptr = P + (size_t)t * QKV_LD + hid * HD;              w = qw; }
        else          { ptr = P + (size_t)t * QKV_LD + HID + (hid - NH) * HD; w = kw; }

        float x1 = (float)ptr[lane];
        float x2 = (float)ptr[lane + 64];
        float ss = x1 * x1 + x2 * x2;
#pragma unroll
        for (int off = 1; off < 64; off <<= 1) ss += __shfl_xor(ss, off);
        const float r = rsqrtf(ss * (1.f / 128.f) + 1e-6f);
        const float n1 = x1 * r * w[lane];
        const float n2 = x2 * r * w[lane + 64];

        const float* cp = cosb + (size_t)t * HD;
        const float* sp = sinb + (size_t)t * HD;
        const float o1 = n1 * cp[lane]      - n2 * sp[lane];
        const float o2 = n2 * cp[lane + 64] + n1 * sp[lane + 64];

        if (hid < NH) {
            _Float16* qrow = QhG + (size_t)t * HID + hid * HD;
            qrow[lane]      = (_Float16)(o1 * QS);
            qrow[lane + 64] = (_Float16)(o2 * QS);
        } else {
            const int b = t / SEQ, s = t % SEQ, kv = hid - NH;
            char* ph = (char*)KhG + ((size_t)(b * NKV + kv) * SEQ + s) * 256;
            const int s7 = s & 7;
            const int d1 = lane, d2 = lane + 64;
            *(_Float16*)(ph + (((d1 >> 3) ^ s7) << 4) + ((d1 & 7) << 1)) = (_Float16)o1;
            *(_Float16*)(ph + (((d2 >> 3) ^ s7) << 4) + ((d2 & 7) << 1)) = (_Float16)o2;
        }
    } else {
        // ------------------- V transpose -------------------
        const int vid = bid - 6 * TOK;      // 0..511
        const int kb = vid & 63;            // 64-token block over TOK
        const int kv = vid >> 6;
        const int tid = threadIdx.x;

#pragma unroll
        for (int r = 0; r < 4; ++r) {
            const int idx = tid + r * 256;      // 0..1023
            const int row = idx >> 4, c8 = idx & 15;
            *(f16x8*)&Ts[row][c8 * 8] =
                *(const f16x8*)(P + (size_t)(kb * 64 + row) * QKV_LD
                                + HID + NKV * HD + kv * HD + c8 * 8);
        }
        __syncthreads();

        const int b  = (kb * 64) / SEQ;
        const int s0 = (kb * 64) % SEQ;
#pragma unroll
        for (int w = 0; w < 4; ++w) {
            const int idx = tid + w * 256;      // 0..1023
            const int d = idx >> 3, c = idx & 7;
            f16x8 pk;
#pragma unroll
            for (int kk = 0; kk < 8; ++kk) pk[kk] = Ts[c * 8 + kk][d];
            char* dst = (char*)VtG + ((size_t)(b * NKV + kv) * 128 + d) * 4096
                        + ((s0 >> 3) + (c ^ (d & 7))) * 16;
            *(f16x8*)dst = pk;
        }
    }
}

// ---------------------------------------------------------------------------
// flash_f16: R14 structure (best measured): K dbuf LDS, V single LDS,
// midbar=vmcnt(4), end-of-iteration staging, XCD-chunked swizzle,
// SWAPPED QK^T (lane-local P-row), cvt_pkrtz P-pack, static-bias softmax.
// PlB row stride 144 B (was 160): 144/4 = 36 ≡ 4 banks mod 32 -> max 2-way
// conflict (free), and 144 = 9*16 keeps ds_read_b128 16B-aligned.
// ---------------------------------------------------------------------------
__global__ __launch_bounds__(256, 2) void flash_f16(
    const _Float16* __restrict__ QhG, const _Float16* __restrict__ KhG,
    const _Float16* __restrict__ VtG, _Float16* __restrict__ OH)
{
    __shared__ char KhL[2][16384];          // [key 64][chunk^swz 16]*16B
    __shared__ char VtL[16384];             // [d 128][chunk^swz 8]*16B
    __shared__ char PlB[4][4608];           // [wave][q 32 rows x 144 B]

    // XCD-chunked swizzle: id%8 = XCD -> give each XCD 64 consecutive tiles
    const int id  = blockIdx.x + 16 * (blockIdx.y + 16 * blockIdx.z);
    const int swz = (id & 7) * 64 + (id >> 3);
    const int qt = swz & 15, h = (swz >> 4) & 15, b = swz >> 8;

    const int hkv = h >> 1;
    const int tid = threadIdx.x, wv = tid >> 6, ln = tid & 63;
    const int lr = ln & 15, lq = ln >> 4;
    const int qbase = qt * 128 + wv * 32;
    const float BIAS = 3.0f * 1.4426950408889634f;   // 3*log2e

    // Q fragments (pre-scaled by scale*log2e in post_qkv)
    f16x8 qh[2][4];
#pragma unroll
    for (int mi = 0; mi < 2; ++mi)
#pragma unroll
        for (int kc = 0; kc < 4; ++kc)
            qh[mi][kc] = *(const f16x8*)(QhG
                + (size_t)(b * SEQ + qbase + mi * 16 + lr) * HID
                + h * HD + kc * 32 + lq * 8);

    f32x4 o_[2][8] = {};
    float rs[2] = {0.f, 0.f};               // per-lane: q-row mi*16 + lr

    const size_t krow = (size_t)(b * NKV + hkv) * SEQ;   // 256B rows
    const size_t vrow = (size_t)(b * NKV + hkv) * 128;   // 4096B rows

    const char* kg[4];
    const char* vg[4];
    int dofs[4];
#pragma unroll
    for (int r = 0; r < 4; ++r) {
        const int idx = tid + r * 256;
        kg[r] = (const char*)KhG + (krow + (idx >> 4)) * 256 + (idx & 15) * 16;
        vg[r] = (const char*)VtG + (vrow + (idx >> 3)) * 4096 + (idx & 7) * 16;
        dofs[r] = (r * 256 + wv * 64) * 16;
    }

#define STAGE_K(buf, kt)                                                      \
    { _Pragma("unroll")                                                       \
      for (int r = 0; r < 4; ++r)                                             \
          gload16(kg[r] + (size_t)(kt) * 16384, &KhL[buf][dofs[r]]); }
#define STAGE_V(kt)                                                           \
    { _Pragma("unroll")                                                       \
      for (int r = 0; r < 4; ++r)                                             \
          gload16(vg[r] + (kt) * 128, &VtL[dofs[r]]); }

    STAGE_K(0, 0);
    STAGE_V(0);
    STAGE_K(1, 1);
    __syncthreads();            // drains vmcnt(0): K(0), V(0), K(1) ready

    const int NT = SEQ / 64;
    for (int kt = 0; kt < NT; ++kt) {
        const int buf = kt & 1;

        // QK^T (SWAPPED): lane holds P-row q = mi*16 + lr,
        // keys nt*16 + lq*4 + r. acc pre-biased by -3*log2e.
        f32x4 s[2][4];
        __builtin_amdgcn_s_setprio(1);
#pragma unroll
        for (int nt = 0; nt < 4; ++nt) {
            const int key = nt * 16 + lr;
            f16x8 kh[4];
#pragma unroll
            for (int kc = 0; kc < 4; ++kc)
                kh[kc] = *(f16x8*)(&KhL[buf][key * 256 +
                                   ((((kc * 4 + lq) ^ (lr & 7))) << 4)]);
#pragma unroll
            for (int mi = 0; mi < 2; ++mi) {
                f32x4 sa = {-BIAS, -BIAS, -BIAS, -BIAS};
#pragma unroll
                for (int kc = 0; kc < 4; ++kc)
                    sa = MFMA(kh[kc], qh[mi][kc], sa);   // A=K, B=Q
                s[mi][nt] = sa;
            }
        }
        __builtin_amdgcn_s_setprio(0);

        // p = 2^s; lane-local row sums; pack pairs -> ds_write_b64
#pragma unroll
        for (int mi = 0; mi < 2; ++mi) {
            float acc = 0.f;
            char* rowp = &PlB[wv][(mi * 16 + lr) * 144 + lq * 8];
#pragma unroll
            for (int nt = 0; nt < 4; ++nt) {
                const float p0 = exp2_fast(s[mi][nt][0]);
                const float p1 = exp2_fast(s[mi][nt][1]);
                const float p2 = exp2_fast(s[mi][nt][2]);
                const float p3 = exp2_fast(s[mi][nt][3]);
                acc += (p0 + p1) + (p2 + p3);
                *(uint2*)(rowp + nt * 32) =
                    make_uint2(cvt_pk2(p0, p1), cvt_pk2(p2, p3));
            }
            rs[mi] += acc;
        }
        f16x8 pa[2][2];
#pragma unroll
        for (int mi = 0; mi < 2; ++mi) {
            pa[mi][0] = *(f16x8*)&PlB[wv][(mi * 16 + lr) * 144 + lq * 16];
            pa[mi][1] = *(f16x8*)&PlB[wv][(mi * 16 + lr) * 144 + 64 + lq * 16];
        }

        // midbar: wait V(kt) only (4 oldest of 8 outstanding); K(kt+1) flies
        if (kt + 1 < NT) {
            asm volatile("s_waitcnt vmcnt(4)" ::: "memory");
        } else {
            asm volatile("s_waitcnt vmcnt(0)" ::: "memory");
        }
        __builtin_amdgcn_s_barrier();

        // PV accumulate: O[32 q][128 d] += P(32x64) x V(64x128)
        __builtin_amdgcn_s_setprio(1);
#pragma unroll
        for (int nt2 = 0; nt2 < 8; ++nt2) {
            const int d0 = nt2 * 16 + lr;
            f16x8 v0 = *(f16x8*)(&VtL[d0 * 128 + ((lq ^ (d0 & 7)) << 4)]);
            f16x8 v1 = *(f16x8*)(&VtL[d0 * 128 + (((4 + lq) ^ (d0 & 7)) << 4)]);
#pragma unroll
            for (int mi = 0; mi < 2; ++mi) {
                o_[mi][nt2] = MFMA(pa[mi][0], v0, o_[mi][nt2]);
                o_[mi][nt2] = MFMA(pa[mi][1], v1, o_[mi][nt2]);
            }
        }
        __builtin_amdgcn_s_setprio(0);

        __syncthreads();        // endbar: drains K(kt+1); V-reads done

        if (kt + 1 < NT) STAGE_V(kt + 1);       // drains at next midbar
        if (kt + 2 < NT) STAGE_K(buf, kt + 2);  // drains at next endbar
    }

    // lane's rs[mi] covers its lq-slice of q-row mi*16+lr: reduce over lq
    float inv[2];
#pragma unroll
    for (int mi = 0; mi < 2; ++mi) {
        float v = rs[mi];
        v += __shfl_xor(v, 16);
        v += __shfl_xor(v, 32);
        inv[mi] = 1.0f / v;
    }
    // redistribute to output-row owners: row q = mi*16 + lq*4 + r is held
    // (as inv[mi]) by lanes with lr == lq*4 + r (any lq group)
    float invq[2][4];
#pragma unroll
    for (int mi = 0; mi < 2; ++mi)
#pragma unroll
        for (int r = 0; r < 4; ++r)
            invq[mi][r] = __shfl(inv[mi], (ln & 48) | (lq * 4 + r));

    // plain row-major fp16 output [token][2048]
#pragma unroll
    for (int mi = 0; mi < 2; ++mi)
#pragma unroll
        for (int r = 0; r < 4; ++r) {
            const int R = b * SEQ + qbase + mi * 16 + lq * 4 + r;
            _Float16* rowp = OH + (size_t)R * HID + h * HD + lr;
#pragma unroll
            for (int nt2 = 0; nt2 < 8; ++nt2)
                rowp[nt2 * 16] = (_Float16)(o_[mi][nt2][r] * invq[mi][r]);
        }
#undef STAGE_K
#undef STAGE_V
}

// ---------------------------------------------------------------------------
extern "C" void kernel_launch(void* const* d_in, const int* in_sizes, int n_in,
                              void* d_out, int out_size, void* d_ws, size_t ws_size,
                              hipStream_t stream)
{
    (void)in_sizes; (void)n_in; (void)out_size; (void)ws_size;
    const float* hidden = (const float*)d_in[0];
    const float* cosb   = (const float*)d_in[1];
    const float* sinb   = (const float*)d_in[2];
    const float* Wq     = (const float*)d_in[3];
    const float* Wk     = (const float*)d_in[4];
    const float* Wv     = (const float*)d_in[5];
    const float* Wo     = (const float*)d_in[6];
    const float* qw     = (const float*)d_in[7];
    const float* kw     = (const float*)d_in[8];
    float* out = (float*)d_out;

    char* ws = (char*)d_ws;
    const size_t MB = 1ull << 20;
    _Float16*  P16   = (_Float16*)(ws);               // 32 MB [4096][4096] fp16
    _Float16*  attnH = (_Float16*)(ws + 32  * MB);    // 16 MB [4096][2048] plain
    _Float16*  HhG   = (_Float16*)(ws + 48  * MB);    // 16 MB [4096][2048] plain
    _Float16*  WallH = (_Float16*)(ws + 64  * MB);    // 16 MB (Wq|Wk|Wv)
    _Float16*  WoH   = (_Float16*)(ws + 80  * MB);    //  8 MB [2048][2048] plain
    _Float16*  KhG   = (_Float16*)(ws + 88  * MB);    //  8 MB (flash-swizzled)
    _Float16*  VtG   = (_Float16*)(ws + 96  * MB);    //  8 MB (flash-swizzled)
    _Float16*  QhG   = (_Float16*)(ws + 104 * MB);    // 16 MB [4096][2048] plain

    const dim3 blk(256);
    conv_all<<<10240, blk, 0, stream>>>(hidden, Wq, Wk, Wv, Wo, HhG, WallH, WoH);

    // fused QKV projection -> fp16 P
    gemm256<true><<<dim3(16, 16), dim3(512), 0, stream>>>(HhG, WallH, P16, QKV_LD, HID);

    // fused norm+rope (q,k) and V transpose
    post_qkv<<<6 * TOK + (TOK / 64) * NKV, blk, 0, stream>>>(
        P16, cosb, sinb, qw, kw, QhG, KhG, VtG);

    flash_f16<<<dim3(SEQ / 128, NH, BATCH), blk, 0, stream>>>(QhG, KhG, VtG, attnH);

    // output projection: 256x128 tiles, full-chip grid
    gemm256x128<<<dim3(16, 16), dim3(512), 0, stream>>>(attnH, WoH, out, HID, HID);
}

// Round 17
// 208.473 us; speedup vs baseline: 1.0534x; 1.0041x over previous
//
#include <hip/hip_runtime.h>
#include <cstdint>

#define SEQ 2048
#define BATCH 2
#define TOK 4096
#define HID 2048
#define NH 16
#define NKV 8
#define HD 128
#define QKV_LD 4096

using f16x8 = __attribute__((ext_vector_type(8))) _Float16;
using f32x4 = __attribute__((ext_vector_type(4))) float;

#define MFMA(a, b, c) __builtin_amdgcn_mfma_f32_16x16x32_f16(a, b, c, 0, 0, 0)

__device__ inline void gload16(const void* g, void* l) {
    __builtin_amdgcn_global_load_lds(
        (const __attribute__((address_space(1))) unsigned*)g,
        (__attribute__((address_space(3))) unsigned*)l, 16, 0, 0);
}

// hardware 2^x — bypasses the ocml exp2f library path (args bounded [-21,12])
__device__ inline float exp2_fast(float x) {
#if __has_builtin(__builtin_amdgcn_exp2f)
    return __builtin_amdgcn_exp2f(x);
#else
    float r;
    asm("v_exp_f32 %0, %1\n\ts_nop 1" : "=v"(r) : "v"(x));
    return r;
#endif
}

// pack two f32 -> one u32 of two f16 (v_cvt_pkrtz_f16_f32)
__device__ inline unsigned cvt_pk2(float a, float b) {
    auto h = __builtin_amdgcn_cvt_pkrtz(a, b);   // __fp16 ext_vector(2)
    return __builtin_bit_cast(unsigned, h);
}

// ---------------------------------------------------------------------------
// conv_all: fp32 operands -> plain row-major fp16: [hidden | Wq | Wk | Wv | Wo]
// ---------------------------------------------------------------------------
__global__ __launch_bounds__(256) void conv_all(
    const float* __restrict__ hidden, const float* __restrict__ Wq,
    const float* __restrict__ Wk, const float* __restrict__ Wv,
    const float* __restrict__ Wo, _Float16* __restrict__ HhG,
    _Float16* __restrict__ WallH, _Float16* __restrict__ WoH)
{
    const int bid = blockIdx.x;
    const float* src;
    _Float16* dst;
    int row;
    if (bid < 4096)      { row = bid;        src = hidden; dst = HhG; }
    else if (bid < 6144) { row = bid - 4096; src = Wq;     dst = WallH; }
    else if (bid < 7168) { row = bid - 6144; src = Wk;     dst = WallH + (size_t)2048 * HID; }
    else if (bid < 8192) { row = bid - 7168; src = Wv;     dst = WallH + (size_t)3072 * HID; }
    else                 { row = bid - 8192; src = Wo;     dst = WoH; }

    const int gch = threadIdx.x;            // chunk 0..255
    const float* s = src + (size_t)row * HID + gch * 8;
    float4 a = *(const float4*)s;
    float4 b = *(const float4*)(s + 4);
    f16x8 v;
    v[0] = (_Float16)a.x; v[1] = (_Float16)a.y;
    v[2] = (_Float16)a.z; v[3] = (_Float16)a.w;
    v[4] = (_Float16)b.x; v[5] = (_Float16)b.y;
    v[6] = (_Float16)b.z; v[7] = (_Float16)b.w;
    *(f16x8*)((char*)dst + (size_t)row * 4096 + gch * 16) = v;
}

// ---------------------------------------------------------------------------
// gemm256<HALF_OUT>: C[m][n] = sum_k A[m][k]*B[n][k], fp16 MFMA, fp32 accum.
// BM=BN=256, BK=64, 512 thr = 8 waves (2M x 4N). 128 KB LDS double-buffer,
// one vmcnt(0)+barrier per K-tile, stage t+1 issued mid-tile. (R14 form.)
// XCD-chunked block swizzle: each XCD owns a 4bm x 8bn rectangle
// (A 4MB + B 8MB resident in its private L2 instead of 18MB scattered).
// ---------------------------------------------------------------------------
template<bool HALF_OUT>
__global__ __launch_bounds__(512, 2) void gemm256(
    const _Float16* __restrict__ Ag, const _Float16* __restrict__ Bg,
    void* __restrict__ Cv, int ldc, int K)
{
    __shared__ char lds[2][4][16384];   // [buf][A0,A1,B0,B1][128 rows][128 B]

    const int tid = threadIdx.x;
    const int wv = tid >> 6, ln = tid & 63;
    const int wm = wv >> 2, wn = wv & 3;
    const int lr = ln & 15, lq = ln >> 4;

    // bijective XCD-chunked swizzle of the 16x16 grid
    const int id  = blockIdx.x + (int)blockIdx.y * 16;
    const int xcd = id & 7, k = id >> 3;
    const int bm = (xcd >> 1) * 4 + (k >> 3);
    const int bn = (xcd & 1) * 8 + (k & 7);

    f32x4 acc[8][4] = {};

    const size_t arow0 = (size_t)bm * 256;
    const size_t brow0 = (size_t)bn * 256;

    const int g = tid & 7;
    uint32_t offA[2][2], offB[2][2];        // [half][issue]
#pragma unroll
    for (int i = 0; i < 2; ++i) {
        const int row = (i * 512 + tid) >> 3;            // 0..127
        const uint32_t sw = (uint32_t)((g ^ (row & 7)) << 4);
        offA[0][i] = (uint32_t)((arow0 + row) * 4096) + sw;
        offA[1][i] = (uint32_t)((arow0 + 128 + row) * 4096) + sw;
        offB[0][i] = (uint32_t)((brow0 + row) * 4096) + sw;
        offB[1][i] = (uint32_t)((brow0 + 128 + row) * 4096) + sw;
    }
    const int dst0 = wv * 64 * 16;          // wave-uniform LDS base (+i*8192)

    const int swz0 = ((lq ^ (lr & 7)) << 4);
    const int swz1 = (((4 + lq) ^ (lr & 7)) << 4);

#define STAGE_ALL(bufsel, t)                                                   \
    { _Pragma("unroll")                                                        \
      for (int i = 0; i < 2; ++i) {                                            \
        gload16((const char*)Ag + offA[0][i] + (size_t)(t) * 128,              \
                &lds[bufsel][0][i * 8192 + dst0]);                             \
        gload16((const char*)Ag + offA[1][i] + (size_t)(t) * 128,              \
                &lds[bufsel][1][i * 8192 + dst0]);                             \
        gload16((const char*)Bg + offB[0][i] + (size_t)(t) * 128,              \
                &lds[bufsel][2][i * 8192 + dst0]);                             \
        gload16((const char*)Bg + offB[1][i] + (size_t)(t) * 128,              \
                &lds[bufsel][3][i * 8192 + dst0]);                             \
      } }

    STAGE_ALL(0, 0);
    asm volatile("s_waitcnt vmcnt(0)" ::: "memory");
    __builtin_amdgcn_s_barrier();

    const int NT = K / 64;
    for (int t = 0; t < NT; ++t) {
        const int buf = t & 1;
        const char* Ab = &lds[buf][wm][0];
        const char* Bb = &lds[buf][2 + (wn >> 1)][(wn & 1) * 64 * 128];

        f16x8 bfr[4][2];
#pragma unroll
        for (int nj = 0; nj < 4; ++nj) {
            bfr[nj][0] = *(const f16x8*)(Bb + (nj * 16 + lr) * 128 + swz0);
            bfr[nj][1] = *(const f16x8*)(Bb + (nj * 16 + lr) * 128 + swz1);
        }

        if (t + 1 < NT) STAGE_ALL(buf ^ 1, t + 1);   // early issue, late drain

        __builtin_amdgcn_s_setprio(1);
#pragma unroll
        for (int mi = 0; mi < 8; ++mi) {
            f16x8 a0 = *(const f16x8*)(Ab + (mi * 16 + lr) * 128 + swz0);
            f16x8 a1 = *(const f16x8*)(Ab + (mi * 16 + lr) * 128 + swz1);
#pragma unroll
            for (int nj = 0; nj < 4; ++nj) {
                acc[mi][nj] = MFMA(a0, bfr[nj][0], acc[mi][nj]);
                acc[mi][nj] = MFMA(a1, bfr[nj][1], acc[mi][nj]);
            }
        }
        __builtin_amdgcn_s_setprio(0);

        asm volatile("s_waitcnt vmcnt(0)" ::: "memory");
        __builtin_amdgcn_s_barrier();
    }
#undef STAGE_ALL

#pragma unroll
    for (int mi = 0; mi < 8; ++mi)
#pragma unroll
        for (int r = 0; r < 4; ++r) {
            const size_t rowoff =
                (size_t)(arow0 + wm * 128 + mi * 16 + lq * 4 + r) * ldc
                + brow0 + wn * 64 + lr;
            if constexpr (HALF_OUT) {
                _Float16* rowp = (_Float16*)Cv + rowoff;
#pragma unroll
                for (int nj = 0; nj < 4; ++nj)
                    rowp[nj * 16] = (_Float16)acc[mi][nj][r];
            } else {
                float* rowp = (float*)Cv + rowoff;
#pragma unroll
                for (int nj = 0; nj < 4; ++nj)
                    rowp[nj * 16] = acc[mi][nj][r];
            }
        }
}

// ---------------------------------------------------------------------------
// gemm256x128: BM=256, BN=128, fp32 out (out-projection, full-chip grid).
// R14 form + the same XCD-chunked swizzle.
// ---------------------------------------------------------------------------
__global__ __launch_bounds__(512, 1) void gemm256x128(
    const _Float16* __restrict__ Ag, const _Float16* __restrict__ Bg,
    float* __restrict__ C, int ldc, int K)
{
    __shared__ char lds[2][3][16384];   // [buf][A0,A1,B][128 rows][128 B]

    const int tid = threadIdx.x;
    const int wv = tid >> 6, ln = tid & 63;
    const int wm = wv >> 1, wn = wv & 1;     // 4M x 2N
    const int lr = ln & 15, lq = ln >> 4;

    const int id  = blockIdx.x + (int)blockIdx.y * 16;
    const int xcd = id & 7, k = id >> 3;
    const int bm = (xcd >> 1) * 4 + (k >> 3);
    const int bn = (xcd & 1) * 8 + (k & 7);

    f32x4 acc[4][4] = {};

    const size_t arow0 = (size_t)bm * 256;
    const size_t brow0 = (size_t)bn * 128;

    const int g = tid & 7;
    uint32_t offA[2][2], offB[2];
#pragma unroll
    for (int i = 0; i < 2; ++i) {
        const int row = (i * 512 + tid) >> 3;
        const uint32_t sw = (uint32_t)((g ^ (row & 7)) << 4);
        offA[0][i] = (uint32_t)((arow0 + row) * 4096) + sw;
        offA[1][i] = (uint32_t)((arow0 + 128 + row) * 4096) + sw;
        offB[i]    = (uint32_t)((brow0 + row) * 4096) + sw;
    }
    const int dst0 = wv * 64 * 16;

    const int swz0 = ((lq ^ (lr & 7)) << 4);
    const int swz1 = (((4 + lq) ^ (lr & 7)) << 4);

#define STAGE_ALL2(bufsel, t)                                                  \
    { _Pragma("unroll")                                                        \
      for (int i = 0; i < 2; ++i) {                                            \
        gload16((const char*)Ag + offA[0][i] + (size_t)(t) * 128,              \
                &lds[bufsel][0][i * 8192 + dst0]);                             \
        gload16((const char*)Ag + offA[1][i] + (size_t)(t) * 128,              \
                &lds[bufsel][1][i * 8192 + dst0]);                             \
        gload16((const char*)Bg + offB[i] + (size_t)(t) * 128,                 \
                &lds[bufsel][2][i * 8192 + dst0]);                             \
      } }

    STAGE_ALL2(0, 0);
    asm volatile("s_waitcnt vmcnt(0)" ::: "memory");
    __builtin_amdgcn_s_barrier();

    const int NT = K / 64;
    for (int t = 0; t < NT; ++t) {
        const int buf = t & 1;
        const char* Ab = &lds[buf][wm >> 1][(wm & 1) * 64 * 128];
        const char* Bb = &lds[buf][2][wn * 64 * 128];

        f16x8 bfr[4][2];
#pragma unroll
        for (int nj = 0; nj < 4; ++nj) {
            bfr[nj][0] = *(const f16x8*)(Bb + (nj * 16 + lr) * 128 + swz0);
            bfr[nj][1] = *(const f16x8*)(Bb + (nj * 16 + lr) * 128 + swz1);
        }

        if (t + 1 < NT) STAGE_ALL2(buf ^ 1, t + 1);

        __builtin_amdgcn_s_setprio(1);
#pragma unroll
        for (int mi = 0; mi < 4; ++mi) {
            f16x8 a0 = *(const f16x8*)(Ab + (mi * 16 + lr) * 128 + swz0);
            f16x8 a1 = *(const f16x8*)(Ab + (mi * 16 + lr) * 128 + swz1);
#pragma unroll
            for (int nj = 0; nj < 4; ++nj) {
                acc[mi][nj] = MFMA(a0, bfr[nj][0], acc[mi][nj]);
                acc[mi][nj] = MFMA(a1, bfr[nj][1], acc[mi][nj]);
            }
        }
        __builtin_amdgcn_s_setprio(0);

        asm volatile("s_waitcnt vmcnt(0)" ::: "memory");
        __builtin_amdgcn_s_barrier();
    }
#undef STAGE_ALL2

#pragma unroll
    for (int mi = 0; mi < 4; ++mi)
#pragma unroll
        for (int r = 0; r < 4; ++r) {
            float* rowp = C + (size_t)(arow0 + wm * 64 + mi * 16 + lq * 4 + r) * ldc
                          + brow0 + wn * 64 + lr;
#pragma unroll
            for (int nj = 0; nj < 4; ++nj)
                rowp[nj * 16] = acc[mi][nj][r];
        }
}

// ---------------------------------------------------------------------------
// post_qkv: fused norm_rope + conv_v (one dispatch).
// Blocks [0, 6*TOK): RMS+RoPE. q heads -> QhG (pre-scaled fp16);
//   k heads -> KhG pre-swizzled fp16.
// Blocks [6*TOK, 6*TOK + 512): V transpose -> VtG pre-swizzled fp16.
// ---------------------------------------------------------------------------
__global__ __launch_bounds__(256) void post_qkv(
    const _Float16* __restrict__ P, const float* __restrict__ cosb,
    const float* __restrict__ sinb, const float* __restrict__ qw,
    const float* __restrict__ kw, _Float16* __restrict__ QhG,
    _Float16* __restrict__ KhG, _Float16* __restrict__ VtG)
{
    __shared__ _Float16 Ts[64][136];
    const int bid = blockIdx.x;

    if (bid < 6 * TOK) {
        // ------------------- norm + rope -------------------
        const int t    = bid / 6;
        const int xb   = bid % 6;
        const int wave = threadIdx.x >> 6;
        const int lane = threadIdx.x & 63;
        const int hid  = xb * 4 + wave;     // 0..23
        const float QS = 0.08838834764831845f * 1.4426950408889634f;

        const _Float16* ptr;
        const float* w;
        if (hid < NH) { ptr = P + (size_t)t * QKV_LD + hid * HD;              w = qw; }
        else          { ptr = P + (size_t)t * QKV_LD + HID + (hid - NH) * HD; w = kw; }

        float x1 = (float)ptr[lane];
        float x2 = (float)ptr[lane + 64];
        float ss = x1 * x1 + x2 * x2;
#pragma unroll
        for (int off = 1; off < 64; off <<= 1) ss += __shfl_xor(ss, off);
        const float r = rsqrtf(ss * (1.f / 128.f) + 1e-6f);
        const float n1 = x1 * r * w[lane];
        const float n2 = x2 * r * w[lane + 64];

        const float* cp = cosb + (size_t)t * HD;
        const float* sp = sinb + (size_t)t * HD;
        const float o1 = n1 * cp[lane]      - n2 * sp[lane];
        const float o2 = n2 * cp[lane + 64] + n1 * sp[lane + 64];

        if (hid < NH) {
            _Float16* qrow = QhG + (size_t)t * HID + hid * HD;
            qrow[lane]      = (_Float16)(o1 * QS);
            qrow[lane + 64] = (_Float16)(o2 * QS);
        } else {
            const int b = t / SEQ, s = t % SEQ, kv = hid - NH;
            char* ph = (char*)KhG + ((size_t)(b * NKV + kv) * SEQ + s) * 256;
            const int s7 = s & 7;
            const int d1 = lane, d2 = lane + 64;
            *(_Float16*)(ph + (((d1 >> 3) ^ s7) << 4) + ((d1 & 7) << 1)) = (_Float16)o1;
            *(_Float16*)(ph + (((d2 >> 3) ^ s7) << 4) + ((d2 & 7) << 1)) = (_Float16)o2;
        }
    } else {
        // ------------------- V transpose -------------------
        const int vid = bid - 6 * TOK;      // 0..511
        const int kb = vid & 63;            // 64-token block over TOK
        const int kv = vid >> 6;
        const int tid = threadIdx.x;

#pragma unroll
        for (int r = 0; r < 4; ++r) {
            const int idx = tid + r * 256;      // 0..1023
            const int row = idx >> 4, c8 = idx & 15;
            *(f16x8*)&Ts[row][c8 * 8] =
                *(const f16x8*)(P + (size_t)(kb * 64 + row) * QKV_LD
                                + HID + NKV * HD + kv * HD + c8 * 8);
        }
        __syncthreads();

        const int b  = (kb * 64) / SEQ;
        const int s0 = (kb * 64) % SEQ;
#pragma unroll
        for (int w = 0; w < 4; ++w) {
            const int idx = tid + w * 256;      // 0..1023
            const int d = idx >> 3, c = idx & 7;
            f16x8 pk;
#pragma unroll
            for (int kk = 0; kk < 8; ++kk) pk[kk] = Ts[c * 8 + kk][d];
            char* dst = (char*)VtG + ((size_t)(b * NKV + kv) * 128 + d) * 4096
                        + ((s0 >> 3) + (c ^ (d & 7))) * 16;
            *(f16x8*)dst = pk;
        }
    }
}

// ---------------------------------------------------------------------------
// flash_f16: R16 structure (best measured): K dbuf LDS, V single LDS,
// midbar=vmcnt(4), end-of-iteration staging, XCD-chunked swizzle,
// SWAPPED QK^T (lane-local P-row), cvt_pkrtz P-pack, static-bias softmax,
// PlB stride 144 B.
// ---------------------------------------------------------------------------
__global__ __launch_bounds__(256, 2) void flash_f16(
    const _Float16* __restrict__ QhG, const _Float16* __restrict__ KhG,
    const _Float16* __restrict__ VtG, _Float16* __restrict__ OH)
{
    __shared__ char KhL[2][16384];          // [key 64][chunk^swz 16]*16B
    __shared__ char VtL[16384];             // [d 128][chunk^swz 8]*16B
    __shared__ char PlB[4][4608];           // [wave][q 32 rows x 144 B]

    // XCD-chunked swizzle: id%8 = XCD -> give each XCD 64 consecutive tiles
    const int id  = blockIdx.x + 16 * (blockIdx.y + 16 * blockIdx.z);
    const int swz = (id & 7) * 64 + (id >> 3);
    const int qt = swz & 15, h = (swz >> 4) & 15, b = swz >> 8;

    const int hkv = h >> 1;
    const int tid = threadIdx.x, wv = tid >> 6, ln = tid & 63;
    const int lr = ln & 15, lq = ln >> 4;
    const int qbase = qt * 128 + wv * 32;
    const float BIAS = 3.0f * 1.4426950408889634f;   // 3*log2e

    // Q fragments (pre-scaled by scale*log2e in post_qkv)
    f16x8 qh[2][4];
#pragma unroll
    for (int mi = 0; mi < 2; ++mi)
#pragma unroll
        for (int kc = 0; kc < 4; ++kc)
            qh[mi][kc] = *(const f16x8*)(QhG
                + (size_t)(b * SEQ + qbase + mi * 16 + lr) * HID
                + h * HD + kc * 32 + lq * 8);

    f32x4 o_[2][8] = {};
    float rs[2] = {0.f, 0.f};               // per-lane: q-row mi*16 + lr

    const size_t krow = (size_t)(b * NKV + hkv) * SEQ;   // 256B rows
    const size_t vrow = (size_t)(b * NKV + hkv) * 128;   // 4096B rows

    const char* kg[4];
    const char* vg[4];
    int dofs[4];
#pragma unroll
    for (int r = 0; r < 4; ++r) {
        const int idx = tid + r * 256;
        kg[r] = (const char*)KhG + (krow + (idx >> 4)) * 256 + (idx & 15) * 16;
        vg[r] = (const char*)VtG + (vrow + (idx >> 3)) * 4096 + (idx & 7) * 16;
        dofs[r] = (r * 256 + wv * 64) * 16;
    }

#define STAGE_K(buf, kt)                                                      \
    { _Pragma("unroll")                                                       \
      for (int r = 0; r < 4; ++r)                                             \
          gload16(kg[r] + (size_t)(kt) * 16384, &KhL[buf][dofs[r]]); }
#define STAGE_V(kt)                                                           \
    { _Pragma("unroll")                                                       \
      for (int r = 0; r < 4; ++r)                                             \
          gload16(vg[r] + (kt) * 128, &VtL[dofs[r]]); }

    STAGE_K(0, 0);
    STAGE_V(0);
    STAGE_K(1, 1);
    __syncthreads();            // drains vmcnt(0): K(0), V(0), K(1) ready

    const int NT = SEQ / 64;
    for (int kt = 0; kt < NT; ++kt) {
        const int buf = kt & 1;

        // QK^T (SWAPPED): lane holds P-row q = mi*16 + lr,
        // keys nt*16 + lq*4 + r. acc pre-biased by -3*log2e.
        f32x4 s[2][4];
        __builtin_amdgcn_s_setprio(1);
#pragma unroll
        for (int nt = 0; nt < 4; ++nt) {
            const int key = nt * 16 + lr;
            f16x8 kh[4];
#pragma unroll
            for (int kc = 0; kc < 4; ++kc)
                kh[kc] = *(f16x8*)(&KhL[buf][key * 256 +
                                   ((((kc * 4 + lq) ^ (lr & 7))) << 4)]);
#pragma unroll
            for (int mi = 0; mi < 2; ++mi) {
                f32x4 sa = {-BIAS, -BIAS, -BIAS, -BIAS};
#pragma unroll
                for (int kc = 0; kc < 4; ++kc)
                    sa = MFMA(kh[kc], qh[mi][kc], sa);   // A=K, B=Q
                s[mi][nt] = sa;
            }
        }
        __builtin_amdgcn_s_setprio(0);

        // p = 2^s; lane-local row sums; pack pairs -> ds_write_b64
#pragma unroll
        for (int mi = 0; mi < 2; ++mi) {
            float acc = 0.f;
            char* rowp = &PlB[wv][(mi * 16 + lr) * 144 + lq * 8];
#pragma unroll
            for (int nt = 0; nt < 4; ++nt) {
                const float p0 = exp2_fast(s[mi][nt][0]);
                const float p1 = exp2_fast(s[mi][nt][1]);
                const float p2 = exp2_fast(s[mi][nt][2]);
                const float p3 = exp2_fast(s[mi][nt][3]);
                acc += (p0 + p1) + (p2 + p3);
                *(uint2*)(rowp + nt * 32) =
                    make_uint2(cvt_pk2(p0, p1), cvt_pk2(p2, p3));
            }
            rs[mi] += acc;
        }
        f16x8 pa[2][2];
#pragma unroll
        for (int mi = 0; mi < 2; ++mi) {
            pa[mi][0] = *(f16x8*)&PlB[wv][(mi * 16 + lr) * 144 + lq * 16];
            pa[mi][1] = *(f16x8*)&PlB[wv][(mi * 16 + lr) * 144 + 64 + lq * 16];
        }

        // midbar: wait V(kt) only (4 oldest of 8 outstanding); K(kt+1) flies
        if (kt + 1 < NT) {
            asm volatile("s_waitcnt vmcnt(4)" ::: "memory");
        } else {
            asm volatile("s_waitcnt vmcnt(0)" ::: "memory");
        }
        __builtin_amdgcn_s_barrier();

        // PV accumulate: O[32 q][128 d] += P(32x64) x V(64x128)
        __builtin_amdgcn_s_setprio(1);
#pragma unroll
        for (int nt2 = 0; nt2 < 8; ++nt2) {
            const int d0 = nt2 * 16 + lr;
            f16x8 v0 = *(f16x8*)(&VtL[d0 * 128 + ((lq ^ (d0 & 7)) << 4)]);
            f16x8 v1 = *(f16x8*)(&VtL[d0 * 128 + (((4 + lq) ^ (d0 & 7)) << 4)]);
#pragma unroll
            for (int mi = 0; mi < 2; ++mi) {
                o_[mi][nt2] = MFMA(pa[mi][0], v0, o_[mi][nt2]);
                o_[mi][nt2] = MFMA(pa[mi][1], v1, o_[mi][nt2]);
            }
        }
        __builtin_amdgcn_s_setprio(0);

        __syncthreads();        // endbar: drains K(kt+1); V-reads done

        if (kt + 1 < NT) STAGE_V(kt + 1);       // drains at next midbar
        if (kt + 2 < NT) STAGE_K(buf, kt + 2);  // drains at next endbar
    }

    // lane's rs[mi] covers its lq-slice of q-row mi*16+lr: reduce over lq
    float inv[2];
#pragma unroll
    for (int mi = 0; mi < 2; ++mi) {
        float v = rs[mi];
        v += __shfl_xor(v, 16);
        v += __shfl_xor(v, 32);
        inv[mi] = 1.0f / v;
    }
    // redistribute to output-row owners: row q = mi*16 + lq*4 + r is held
    // (as inv[mi]) by lanes with lr == lq*4 + r (any lq group)
    float invq[2][4];
#pragma unroll
    for (int mi = 0; mi < 2; ++mi)
#pragma unroll
        for (int r = 0; r < 4; ++r)
            invq[mi][r] = __shfl(inv[mi], (ln & 48) | (lq * 4 + r));

    // plain row-major fp16 output [token][2048]
#pragma unroll
    for (int mi = 0; mi < 2; ++mi)
#pragma unroll
        for (int r = 0; r < 4; ++r) {
            const int R = b * SEQ + qbase + mi * 16 + lq * 4 + r;
            _Float16* rowp = OH + (size_t)R * HID + h * HD + lr;
#pragma unroll
            for (int nt2 = 0; nt2 < 8; ++nt2)
                rowp[nt2 * 16] = (_Float16)(o_[mi][nt2][r] * invq[mi][r]);
        }
#undef STAGE_K
#undef STAGE_V
}

// ---------------------------------------------------------------------------
extern "C" void kernel_launch(void* const* d_in, const int* in_sizes, int n_in,
                              void* d_out, int out_size, void* d_ws, size_t ws_size,
                              hipStream_t stream)
{
    (void)in_sizes; (void)n_in; (void)out_size; (void)ws_size;
    const float* hidden = (const float*)d_in[0];
    const float* cosb   = (const float*)d_in[1];
    const float* sinb   = (const float*)d_in[2];
    const float* Wq     = (const float*)d_in[3];
    const float* Wk     = (const float*)d_in[4];
    const float* Wv     = (const float*)d_in[5];
    const float* Wo     = (const float*)d_in[6];
    const float* qw     = (const float*)d_in[7];
    const float* kw     = (const float*)d_in[8];
    float* out = (float*)d_out;

    char* ws = (char*)d_ws;
    const size_t MB = 1ull << 20;
    _Float16*  P16   = (_Float16*)(ws);               // 32 MB [4096][4096] fp16
    _Float16*  attnH = (_Float16*)(ws + 32  * MB);    // 16 MB [4096][2048] plain
    _Float16*  HhG   = (_Float16*)(ws + 48  * MB);    // 16 MB [4096][2048] plain
    _Float16*  WallH = (_Float16*)(ws + 64  * MB);    // 16 MB (Wq|Wk|Wv)
    _Float16*  WoH   = (_Float16*)(ws + 80  * MB);    //  8 MB [2048][2048] plain
    _Float16*  KhG   = (_Float16*)(ws + 88  * MB);    //  8 MB (flash-swizzled)
    _Float16*  VtG   = (_Float16*)(ws + 96  * MB);    //  8 MB (flash-swizzled)
    _Float16*  QhG   = (_Float16*)(ws + 104 * MB);    // 16 MB [4096][2048] plain

    const dim3 blk(256);
    conv_all<<<10240, blk, 0, stream>>>(hidden, Wq, Wk, Wv, Wo, HhG, WallH, WoH);

    // fused QKV projection -> fp16 P
    gemm256<true><<<dim3(16, 16), dim3(512), 0, stream>>>(HhG, WallH, P16, QKV_LD, HID);

    // fused norm+rope (q,k) and V transpose
    post_qkv<<<6 * TOK + (TOK / 64) * NKV, blk, 0, stream>>>(
        P16, cosb, sinb, qw, kw, QhG, KhG, VtG);

    flash_f16<<<dim3(SEQ / 128, NH, BATCH), blk, 0, stream>>>(QhG, KhG, VtG, attnH);

    // output projection: 256x128 tiles, full-chip grid
    gemm256x128<<<dim3(16, 16), dim3(512), 0, stream>>>(attnH, WoH, out, HID, HID);
}